// Round 17
// baseline (563.254 us; speedup 1.0000x reference)
//
#include <hip/hip_runtime.h>

#define NN 100000
#define NE 1250000
#define NR 8
#define DD 64
#define TILE 128
#define NTILES 782                 // ceil(100000/128)
#define NBUCKETS (NR * NTILES)     // 6256 dst-buckets (rel, dst-tile)
#define CAP 512                    // sort-chunk size (Poisson(200): 1 chunk typical)
#define HROW 72                    // bf16 LDS row stride (144B: conflict-free b128 frags)
#define EPSB 1e-5f

typedef unsigned short u16;
typedef unsigned int u32;
typedef __attribute__((ext_vector_type(8))) short short8;   // 8 bf16 = 4 VGPR (MFMA A/B frag)
typedef __attribute__((ext_vector_type(4))) float f32x4;    // MFMA C/D frag

static __device__ __forceinline__ float b2f_lo(u32 v) { return __uint_as_float(v << 16); }
static __device__ __forceinline__ float b2f_hi(u32 v) { return __uint_as_float(v & 0xffff0000u); }
static __device__ __forceinline__ u16 f2b(float f) {
    u32 u = __float_as_uint(f);
    u += 0x7fffu + ((u >> 16) & 1u);   // round-to-nearest-even
    return (u16)(u >> 16);
}
static __device__ __forceinline__ u32 pk(float a, float b) {
    return (u32)f2b(a) | ((u32)f2b(b) << 16);
}
// NOTE (measured R11/R12/R15): spill wall at ~8 live uint4 + acc. The 512-thread
// quarter-row gather keeps 4-edge unroll within that budget (8 uint4 + acc[16]).
static __device__ __forceinline__ void acc4(float* acc, uint4 v0, uint4 v1) {
    acc[0]  += b2f_lo(v0.x); acc[1]  += b2f_hi(v0.x);
    acc[2]  += b2f_lo(v0.y); acc[3]  += b2f_hi(v0.y);
    acc[4]  += b2f_lo(v0.z); acc[5]  += b2f_hi(v0.z);
    acc[6]  += b2f_lo(v0.w); acc[7]  += b2f_hi(v0.w);
    acc[8]  += b2f_lo(v1.x); acc[9]  += b2f_hi(v1.x);
    acc[10] += b2f_lo(v1.y); acc[11] += b2f_hi(v1.y);
    acc[12] += b2f_lo(v1.z); acc[13] += b2f_hi(v1.z);
    acc[14] += b2f_lo(v1.w); acc[15] += b2f_hi(v1.w);
}

// ---------------- fp32 -> bf16 copy of x ----------------

__global__ void cvt_kernel(const float* __restrict__ in, u16* __restrict__ outb) {
    int i = blockIdx.x * 256 + threadIdx.x;
    if (i < NN * DD / 8) {
        float4 a = *(const float4*)&in[i * 8];
        float4 b = *(const float4*)&in[i * 8 + 4];
        uint4 o;
        o.x = pk(a.x, a.y); o.y = pk(a.z, a.w);
        o.z = pk(b.x, b.y); o.w = pk(b.z, b.w);
        *(uint4*)&outb[i * 8] = o;
    }
}

// ---------------- weight pre-transpose: Wt[d][k] bf16, all 36 matrices ----------------

__global__ void wt_kernel(const float* __restrict__ W1, const float* __restrict__ rW1,
                          const float* __restrict__ W2, const float* __restrict__ rW2,
                          u16* __restrict__ wt1g, u16* __restrict__ wt2g) {
    int m = blockIdx.x;                  // 0..35
    int i = m / 18, rest = m % 18;
    int set = rest / 9, r = rest % 9;
    const float* W = (set == 0)
        ? ((r < NR) ? (W1 + ((size_t)i * NR + r) * DD * DD) : (rW1 + (size_t)i * DD * DD))
        : ((r < NR) ? (W2 + ((size_t)i * NR + r) * DD * DD) : (rW2 + (size_t)i * DD * DD));
    u32* dst = (u32*)((set == 0 ? wt1g : wt2g) + ((size_t)i * 9 + r) * DD * DD);
    for (int j = threadIdx.x; j < DD * 32; j += 256) {
        int d = j >> 5, kp = j & 31;
        dst[j] = pk(W[(2 * kp) * DD + d], W[(2 * kp + 1) * DD + d]);
    }
}

// ---------------- dst-CSR build (once per call) ----------------

__global__ void count_kernel(const int* __restrict__ dst,
                             const int* __restrict__ et,
                             int* __restrict__ cnt) {
    int i = blockIdx.x * 256 + threadIdx.x;
    if (i < NE) atomicAdd(&cnt[et[i] * NTILES + (dst[i] >> 7)], 1);
}

__global__ void scan_kernel(const int* __restrict__ cnt, int* __restrict__ off, int n) {
    __shared__ int ts[1024];
    int t = threadIdx.x;
    int v[8];
    int s = 0;
#pragma unroll
    for (int j = 0; j < 8; j++) {
        int idx = t * 8 + j;
        int c = (idx < n) ? cnt[idx] : 0;
        v[j] = s;
        s += c;
    }
    ts[t] = s;
    __syncthreads();
    for (int d = 1; d < 1024; d <<= 1) {
        int add = (t >= d) ? ts[t - d] : 0;
        __syncthreads();
        ts[t] += add;
        __syncthreads();
    }
    int base = (t > 0) ? ts[t - 1] : 0;
#pragma unroll
    for (int j = 0; j < 8; j++) {
        int idx = t * 8 + j;
        if (idx < n) off[idx] = base + v[j];
    }
    if (t == 1023) off[n] = ts[1023];
}

__global__ void fill_kernel(const int* __restrict__ src, const int* __restrict__ dst,
                            const int* __restrict__ et, const int* __restrict__ off,
                            int* __restrict__ cursor, int* __restrict__ ep) {
    int i = blockIdx.x * 256 + threadIdx.x;
    if (i < NE) {
        int d = dst[i];
        int b = et[i] * NTILES + (d >> 7);
        int pos = off[b] + atomicAdd(&cursor[b], 1);
        ep[pos] = (src[i] << 8) | (d & 127);
    }
}

// ---------------- gemm1: 512-thread quarter-row gather -> bf16 LDS -> MFMA, BN stats ----------------

__launch_bounds__(512, 6)
__global__ void gemm1_kernel(const u16* __restrict__ xb,
                             const int* __restrict__ ep, const int* __restrict__ off,
                             const u16* __restrict__ wt1, const float* __restrict__ b1l,
                             const float* __restrict__ rb1l,
                             u16* __restrict__ zb, float* __restrict__ stats) {
    __shared__ u16 hsb[TILE * HROW];      // 18KB bf16 h-tile (then reused for z)
    __shared__ int seS[CAP], seD[CAP];
    __shared__ int shist[TILE], scur[TILE];
    __shared__ int soff[TILE + 1];
    __shared__ float red[2 * DD];
    int r = blockIdx.y;
    bool root = (r == NR);
    int n0 = blockIdx.x * TILE;
    int tid = threadIdx.x;

    int wv2 = tid >> 6;  // 0..7: MFMA wave -> rows wv2*16..+15
    int l  = tid & 63;
    int lr = l & 15;     // A row / B col / D col
    int lg = l >> 4;     // k-group / D row-group

    if (tid < 128) red[tid] = 0.f;

    if (!root) {
        int b = r * NTILES + blockIdx.x;
        int e0 = off[b], e1 = off[b + 1];
        int m = e1 - e0;
        int slot = tid >> 2, quarter = tid & 3;   // 4-lane group = one full 128B x-row
        int c0 = quarter * 16;
        float acc[16];
#pragma unroll
        for (int j = 0; j < 16; j++) acc[j] = 0.f;

        for (int base = 0; base < m; base += CAP) {
            int cnt = min(m - base, CAP);
            if (tid < TILE) shist[tid] = 0;
            __syncthreads();                       // (a) hist zeroed; prev gather done
            for (int i = tid; i < cnt; i += 512) {
                int p = ep[e0 + base + i];
                seS[i] = p;
                atomicAdd(&shist[p & 127], 1);
            }
            __syncthreads();                       // (b) hist complete
            if (tid < 64) {
                // single-wave scan of 128 counters: lane t owns entries t and t+64
                int c0s = shist[tid], c1s = shist[tid + 64];
                int s0 = c0s, s1 = c1s;
#pragma unroll
                for (int d = 1; d < 64; d <<= 1) {
                    int t0 = __shfl_up(s0, d);
                    int t1 = __shfl_up(s1, d);
                    if (tid >= d) { s0 += t0; s1 += t1; }
                }
                int tot0 = __shfl(s0, 63);
                soff[tid + 1]  = s0;
                soff[tid + 65] = tot0 + s1;
                if (tid == 0) soff[0] = 0;
                scur[tid]      = s0 - c0s;
                scur[tid + 64] = tot0 + s1 - c1s;
            }
            __syncthreads();                       // (c) soff/scur ready
            for (int i = tid; i < cnt; i += 512) {
                int p = seS[i];
                seD[atomicAdd(&scur[p & 127], 1)] = p;
            }
            __syncthreads();                       // (d) seD sorted
            int sb = soff[slot], se = soff[slot + 1];
            int e = sb;
            for (; e + 4 <= se; e += 4) {          // 4-edge unroll: 8 uint4 in flight
                const u16* x0p = &xb[(size_t)(seD[e]     >> 8) * DD + c0];
                const u16* x1p = &xb[(size_t)(seD[e + 1] >> 8) * DD + c0];
                const u16* x2p = &xb[(size_t)(seD[e + 2] >> 8) * DD + c0];
                const u16* x3p = &xb[(size_t)(seD[e + 3] >> 8) * DD + c0];
                uint4 a0 = *(const uint4*)(x0p), a1 = *(const uint4*)(x0p + 8);
                uint4 b0 = *(const uint4*)(x1p), b1 = *(const uint4*)(x1p + 8);
                uint4 cc0 = *(const uint4*)(x2p), cc1 = *(const uint4*)(x2p + 8);
                uint4 d0 = *(const uint4*)(x3p), d1 = *(const uint4*)(x3p + 8);
                acc4(acc, a0, a1);
                acc4(acc, b0, b1);
                acc4(acc, cc0, cc1);
                acc4(acc, d0, d1);
            }
            for (; e < se; e++) {
                const u16* xr = &xb[(size_t)(seD[e] >> 8) * DD + c0];
                acc4(acc, *(const uint4*)(xr), *(const uint4*)(xr + 8));
            }
        }
        // pack h to bf16 (16 floats -> 2 uint4)
        u32 pw[8];
#pragma unroll
        for (int j = 0; j < 8; j++) pw[j] = pk(acc[2 * j], acc[2 * j + 1]);
        u16* hrow = &hsb[slot * HROW + c0];
        *(uint4*)(hrow)     = make_uint4(pw[0], pw[1], pw[2], pw[3]);
        *(uint4*)(hrow + 8) = make_uint4(pw[4], pw[5], pw[6], pw[7]);
    } else {
        for (int idx = tid; idx < TILE * 8; idx += 512) {
            int row = idx >> 3, q = idx & 7;
            int n = n0 + row;
            uint4 v = make_uint4(0, 0, 0, 0);
            if (n < NN) v = *(const uint4*)&xb[(size_t)n * DD + q * 8];
            *(uint4*)&hsb[row * HROW + q * 8] = v;
        }
    }

    // B fragments from pre-transposed global Wt (L2-hot), short liveness: right before MFMA
    const u16* wtg = wt1 + (size_t)r * DD * DD;
    short8 bfrg[2][4];
#pragma unroll
    for (int ks = 0; ks < 2; ks++)
#pragma unroll
        for (int ct = 0; ct < 4; ct++)
            bfrg[ks][ct] = *(const short8*)&wtg[(ct * 16 + lr) * DD + ks * 32 + lg * 8];
    __syncthreads();

    // ---- MFMA: 8 waves, wave wv2 owns rows wv2*16..+15, all 64 cols ----
    f32x4 dacc[4];
#pragma unroll
    for (int ct = 0; ct < 4; ct++) dacc[ct] = (f32x4){0.f, 0.f, 0.f, 0.f};

#pragma unroll
    for (int ks = 0; ks < 2; ks++) {
        short8 afr = *(const short8*)&hsb[(wv2 * 16 + lr) * HROW + ks * 32 + lg * 8];
#pragma unroll
        for (int ct = 0; ct < 4; ct++)
            dacc[ct] = __builtin_amdgcn_mfma_f32_16x16x32_bf16(afr, bfrg[ks][ct], dacc[ct], 0, 0, 0);
    }

    // bias + BN stats (per-lane cols 16ct+lr, rows wv2*16+lg*4+i)
    const float* bvec = root ? rb1l : (b1l + r * DD);
    float bv4[4], s1v[4], s2v[4];
#pragma unroll
    for (int ct = 0; ct < 4; ct++) { bv4[ct] = bvec[16 * ct + lr]; s1v[ct] = 0.f; s2v[ct] = 0.f; }
#pragma unroll
    for (int ct = 0; ct < 4; ct++)
#pragma unroll
        for (int i = 0; i < 4; i++) {
            float v = dacc[ct][i] + bv4[ct];
            dacc[ct][i] = v;
            int n = n0 + wv2 * 16 + lg * 4 + i;
            if (n < NN) { s1v[ct] += v; s2v[ct] += v * v; }
        }
#pragma unroll
    for (int ct = 0; ct < 4; ct++) {
        float a = s1v[ct], bq = s2v[ct];
        a += __shfl_xor(a, 16); bq += __shfl_xor(bq, 16);
        a += __shfl_xor(a, 32); bq += __shfl_xor(bq, 32);
        if (lg == 0) {
            atomicAdd(&red[16 * ct + lr], a);
            atomicAdd(&red[64 + 16 * ct + lr], bq);
        }
    }
    __syncthreads();   // hsb reads done; red complete

    // scatter z (bf16) into hsb, then coalesced flush
#pragma unroll
    for (int ct = 0; ct < 4; ct++)
#pragma unroll
        for (int i = 0; i < 4; i++)
            hsb[(wv2 * 16 + lg * 4 + i) * HROW + 16 * ct + lr] = f2b(dacc[ct][i]);
    __syncthreads();

    u16* zout = zb + (size_t)r * NN * DD;
    for (int idx = tid; idx < TILE * 8; idx += 512) {
        int row = idx >> 3, q = idx & 7;
        int n = n0 + row;
        if (n < NN)
            *(uint4*)&zout[(size_t)n * DD + q * 8] = *(const uint4*)&hsb[row * HROW + q * 8];
    }
    if (tid < 64) {
        atomicAdd(&stats[r * DD + tid], red[tid]);
        atomicAdd(&stats[576 + r * DD + tid], red[64 + tid]);
    }
}

// ---------------- finalize: BN affine + fused const bias ----------------

__global__ void finalize_kernel(const float* __restrict__ stats,
                                const float* __restrict__ g1l, const float* __restrict__ be1l,
                                const float* __restrict__ rg1l, const float* __restrict__ rbe1l,
                                const float* __restrict__ b2l, const float* __restrict__ rb2l,
                                const float* __restrict__ biasl,
                                float* __restrict__ affine, float* __restrict__ constd) {
    int t = threadIdx.x;
    if (t < 576) {
        int r = t >> 6, d = t & 63;
        float mean = stats[t] * (1.f / NN);
        float var = fmaxf(stats[576 + t] * (1.f / NN) - mean * mean, 0.f);
        float g  = (r < NR) ? g1l[r * DD + d]  : rg1l[d];
        float be = (r < NR) ? be1l[r * DD + d] : rbe1l[d];
        float sc = g * rsqrtf(var + EPSB);
        affine[t] = sc;
        affine[576 + t] = be - mean * sc;
        if (r == 0) {
            float cd = rb2l[d] + biasl[d];
#pragma unroll
            for (int rr = 0; rr < NR; rr++) cd += b2l[rr * DD + d];
            constd[d] = cd;
        }
    }
}

// ---------------- pass2: MFMA out = sum_r relu(bn(z_r)) @ W2_r + const ----------------

__launch_bounds__(256, 4)
__global__ void pass2_kernel(const u16* __restrict__ zb, const u16* __restrict__ wt2,
                             const float* __restrict__ affine, const float* __restrict__ constd,
                             float* __restrict__ outf, u16* __restrict__ outb,
                             int emit_bf16_relu) {
    __shared__ u16 zsb[TILE * HROW];      // 18KB bf16 activated z-tile (reused for output)
    __shared__ u16 wtb[DD * HROW];        // 9KB Wt[d][k]
    int n0 = blockIdx.x * TILE;
    int tid = threadIdx.x;
    int srow = tid >> 3;          // staging row base (0..31), rows srow+32q
    int sc0 = (tid & 7) * 8;      // staging col base

    int wv = tid >> 6;
    int l  = tid & 63;
    int lr = l & 15;
    int lg = l >> 4;

    f32x4 dacc[2][4];
#pragma unroll
    for (int rt = 0; rt < 2; rt++)
#pragma unroll
        for (int ct = 0; ct < 4; ct++) dacc[rt][ct] = (f32x4){0.f, 0.f, 0.f, 0.f};

    uint4 preA[4], preB[4];
    u32 wreg[8];
#pragma unroll
    for (int q = 0; q < 4; q++) {
        int n = n0 + srow + 32 * q;
        preA[q] = (n < NN) ? *(const uint4*)&zb[(size_t)n * DD + sc0] : make_uint4(0, 0, 0, 0);
        preB[q] = (n < NN) ? *(const uint4*)&zb[(size_t)NN * DD + (size_t)n * DD + sc0]
                           : make_uint4(0, 0, 0, 0);
    }
    // prologue: W2t[0] into registers
    {
        const u32* wsrc = (const u32*)wt2;
#pragma unroll
        for (int j = 0; j < 8; j++) wreg[j] = wsrc[tid + 256 * j];
    }

#pragma unroll
    for (int r = 0; r < 9; r++) {
        uint4* cur = (r & 1) ? preB : preA;   // compile-time after unroll
        float4 aLo = *(const float4*)&affine[r * DD + sc0];
        float4 aHi = *(const float4*)&affine[r * DD + sc0 + 4];
        float4 cLo = *(const float4*)&affine[576 + r * DD + sc0];
        float4 cHi = *(const float4*)&affine[576 + r * DD + sc0 + 4];
        __syncthreads();   // previous iteration's MFMA frag-reads done
        // write activated tile (bf16) into zsb
#pragma unroll
        for (int q = 0; q < 4; q++) {
            uint4 vv = cur[q];
            float a0 = fmaxf(fmaf(b2f_lo(vv.x), aLo.x, cLo.x), 0.f);
            float a1 = fmaxf(fmaf(b2f_hi(vv.x), aLo.y, cLo.y), 0.f);
            float a2 = fmaxf(fmaf(b2f_lo(vv.y), aLo.z, cLo.z), 0.f);
            float a3 = fmaxf(fmaf(b2f_hi(vv.y), aLo.w, cLo.w), 0.f);
            float a4 = fmaxf(fmaf(b2f_lo(vv.z), aHi.x, cHi.x), 0.f);
            float a5 = fmaxf(fmaf(b2f_hi(vv.z), aHi.y, cHi.y), 0.f);
            float a6 = fmaxf(fmaf(b2f_lo(vv.w), aHi.z, cHi.z), 0.f);
            float a7 = fmaxf(fmaf(b2f_hi(vv.w), aHi.w, cHi.w), 0.f);
            uint4 o = make_uint4(pk(a0, a1), pk(a2, a3), pk(a4, a5), pk(a6, a7));
            *(uint4*)&zsb[(srow + 32 * q) * HROW + sc0] = o;
        }
        // write W2t from prefetched registers (loaded during previous MFMA)
        {
            int row = tid >> 5, q = tid & 31;     // tid -> (row, dword) ; 8 rows per burst
#pragma unroll
            for (int j = 0; j < 8; j++)
                ((u32*)&wtb[(row + 8 * j) * HROW])[q] = wreg[j];
        }
        __syncthreads();
        // issue W2t loads for r+1 and z loads for r+2 (fly during MFMA)
        if (r + 1 < 9) {
            const u32* wsrc = (const u32*)(wt2 + (size_t)(r + 1) * DD * DD);
#pragma unroll
            for (int j = 0; j < 8; j++) wreg[j] = wsrc[tid + 256 * j];
        }
        if (r + 2 < 9) {
            const u16* zp = zb + (size_t)(r + 2) * NN * DD;
#pragma unroll
            for (int q = 0; q < 4; q++) {
                int n = n0 + srow + 32 * q;
                cur[q] = (n < NN) ? *(const uint4*)&zp[(size_t)n * DD + sc0]
                                  : make_uint4(0, 0, 0, 0);
            }
        }
        // MFMA
#pragma unroll
        for (int ks = 0; ks < 2; ks++) {
            short8 afr[2];
#pragma unroll
            for (int rt = 0; rt < 2; rt++)
                afr[rt] = *(const short8*)&zsb[(wv * 32 + rt * 16 + lr) * HROW + ks * 32 + lg * 8];
#pragma unroll
            for (int ct = 0; ct < 4; ct++) {
                short8 bfr = *(const short8*)&wtb[(ct * 16 + lr) * HROW + ks * 32 + lg * 8];
                dacc[0][ct] = __builtin_amdgcn_mfma_f32_16x16x32_bf16(afr[0], bfr, dacc[0][ct], 0, 0, 0);
                dacc[1][ct] = __builtin_amdgcn_mfma_f32_16x16x32_bf16(afr[1], bfr, dacc[1][ct], 0, 0, 0);
            }
        }
    }

    float cd4[4];
#pragma unroll
    for (int ct = 0; ct < 4; ct++) cd4[ct] = constd[16 * ct + lr];

    if (emit_bf16_relu) {
        __syncthreads();
#pragma unroll
        for (int rt = 0; rt < 2; rt++)
#pragma unroll
            for (int ct = 0; ct < 4; ct++)
#pragma unroll
                for (int i = 0; i < 4; i++) {
                    float v = fmaxf(dacc[rt][ct][i] + cd4[ct], 0.f);
                    zsb[(wv * 32 + rt * 16 + lg * 4 + i) * HROW + 16 * ct + lr] = f2b(v);
                }
        __syncthreads();
        for (int idx = tid; idx < TILE * 8; idx += 256) {
            int row = idx >> 3, q = idx & 7;
            int n = n0 + row;
            if (n < NN)
                *(uint4*)&outb[(size_t)n * DD + q * 8] = *(const uint4*)&zsb[row * HROW + q * 8];
        }
    } else {
        float* zf = (float*)zsb;   // 128 x 34 f32 fits in 18KB
#pragma unroll
        for (int h = 0; h < 2; h++) {
            __syncthreads();
#pragma unroll
            for (int rt = 0; rt < 2; rt++)
#pragma unroll
                for (int cc = 0; cc < 2; cc++) {
                    int ct = 2 * h + cc;
#pragma unroll
                    for (int i = 0; i < 4; i++)
                        zf[(wv * 32 + rt * 16 + lg * 4 + i) * 34 + 16 * cc + lr] =
                            dacc[rt][ct][i] + cd4[ct];
                }
            __syncthreads();
            for (int idx = tid; idx < TILE * 8; idx += 256) {
                int row = idx >> 3, q = idx & 7;
                int n = n0 + row;
                if (n < NN)
                    *(float4*)&outf[(size_t)n * DD + 32 * h + q * 4] =
                        *(const float4*)&zf[row * 34 + q * 4];
            }
        }
    }
}

// ---------------- host ----------------

extern "C" void kernel_launch(void* const* d_in, const int* in_sizes, int n_in,
                              void* d_out, int out_size, void* d_ws, size_t ws_size,
                              hipStream_t stream) {
    (void)in_sizes; (void)n_in; (void)out_size;

    const float* x0   = (const float*)d_in[0];
    const int*   ei   = (const int*)d_in[1];
    const int*   et   = (const int*)d_in[2];
    const float* W1   = (const float*)d_in[3];
    const float* b1   = (const float*)d_in[4];
    const float* g1   = (const float*)d_in[5];
    const float* be1  = (const float*)d_in[6];
    const float* W2   = (const float*)d_in[7];
    const float* b2   = (const float*)d_in[8];
    const float* rW1  = (const float*)d_in[9];
    const float* rb1  = (const float*)d_in[10];
    const float* rg1  = (const float*)d_in[11];
    const float* rbe1 = (const float*)d_in[12];
    const float* rW2  = (const float*)d_in[13];
    const float* rb2  = (const float*)d_in[14];
    const float* bias = (const float*)d_in[15];
    float* out = (float*)d_out;

    char* ws = (char*)d_ws;
    size_t zelems = (size_t)9 * NN * DD;
    u16* zb   = (u16*)ws;                             // 9*NN*DD bf16
    u16* xb   = zb + zelems;                          // NN*DD bf16
    u16* wt1g = xb + (size_t)NN * DD;                 // 9*4096 bf16 x2 layers
    u16* wt2g = wt1g + 18 * DD * DD;
    float* stats  = (float*)(wt2g + 18 * DD * DD);    // 2*1152 (per-layer)
    float* affine = stats + 2304;                     // 1152
    float* constd = affine + 1152;                    // 64
    int* cnt    = (int*)(constd + 64);                // NBUCKETS
    int* cursor = cnt + NBUCKETS;                     // NBUCKETS
    int* off    = cursor + NBUCKETS;                  // NBUCKETS+1
    int* ep     = off + NBUCKETS + 1;                 // NE

    size_t need = (zelems + (size_t)NN * DD + 36 * DD * DD) * 2
                + (2304 + 1152 + 64) * 4
                + ((size_t)3 * NBUCKETS + 1 + NE) * 4;
    if (ws_size < need) return;

    cvt_kernel<<<(NN * DD / 8 + 255) / 256, 256, 0, stream>>>(x0, xb);
    wt_kernel<<<36, 256, 0, stream>>>(W1, rW1, W2, rW2, wt1g, wt2g);
    hipMemsetAsync(cnt, 0, sizeof(int) * 2 * NBUCKETS, stream);
    hipMemsetAsync(stats, 0, sizeof(float) * 2304, stream);
    count_kernel<<<(NE + 255) / 256, 256, 0, stream>>>(ei + NE, et, cnt);
    scan_kernel<<<1, 1024, 0, stream>>>(cnt, off, NBUCKETS);
    fill_kernel<<<(NE + 255) / 256, 256, 0, stream>>>(ei, ei + NE, et, off, cursor, ep);

    for (int i = 0; i < 2; i++) {
        gemm1_kernel<<<dim3(NTILES, 9), 512, 0, stream>>>(
            xb, ep, off,
            wt1g + (size_t)i * 9 * DD * DD,
            b1 + (size_t)i * NR * DD, rb1 + (size_t)i * DD,
            zb, stats + (size_t)i * 1152);
        finalize_kernel<<<1, 576, 0, stream>>>(
            stats + (size_t)i * 1152,
            g1 + (size_t)i * NR * DD, be1 + (size_t)i * NR * DD,
            rg1 + (size_t)i * DD, rbe1 + (size_t)i * DD,
            b2 + (size_t)i * NR * DD, rb2 + (size_t)i * DD, bias + (size_t)i * DD,
            affine, constd);
        pass2_kernel<<<NTILES, 256, 0, stream>>>(
            zb, wt2g + (size_t)i * 9 * DD * DD,
            affine, constd, out, xb, (i == 0) ? 1 : 0);
    }
}

// Round 18
// 521.503 us; speedup vs baseline: 1.0801x; 1.0801x over previous
//
#include <hip/hip_runtime.h>

#define NN 100000
#define NE 1250000
#define NR 8
#define DD 64
#define TILE 128
#define NTILES 782                 // ceil(100000/128)
#define NBUCKETS (NR * NTILES)     // 6256 dst-buckets (rel, dst-tile)
#define CAP 512                    // sort-chunk size (Poisson(200): 1 chunk typical)
#define HROW 72                    // bf16 LDS row stride (144B: conflict-free b128 frags)
#define EPSB 1e-5f

typedef unsigned short u16;
typedef unsigned int u32;
typedef __attribute__((ext_vector_type(8))) short short8;   // 8 bf16 = 4 VGPR (MFMA A/B frag)
typedef __attribute__((ext_vector_type(4))) float f32x4;    // MFMA C/D frag

static __device__ __forceinline__ float b2f_lo(u32 v) { return __uint_as_float(v << 16); }
static __device__ __forceinline__ float b2f_hi(u32 v) { return __uint_as_float(v & 0xffff0000u); }
static __device__ __forceinline__ u16 f2b(float f) {
    u32 u = __float_as_uint(f);
    u += 0x7fffu + ((u >> 16) & 1u);   // round-to-nearest-even
    return (u16)(u >> 16);
}
static __device__ __forceinline__ u32 pk(float a, float b) {
    return (u32)f2b(a) | ((u32)f2b(b) << 16);
}
// NOTE (measured R11/R12/R15/R17): any launch_bounds that caps VGPR below ~60
// spills the gather accumulators (WRITE balloons past z=116MB) and regresses.
// Spill-free configs: (256,4) -> 60 VGPR, (512,4) expected similar. The "6"
// min-waves variants cap at 40 VGPR and ALWAYS spill. Do not use.
static __device__ __forceinline__ void acc4(float* acc, uint4 v0, uint4 v1) {
    acc[0]  += b2f_lo(v0.x); acc[1]  += b2f_hi(v0.x);
    acc[2]  += b2f_lo(v0.y); acc[3]  += b2f_hi(v0.y);
    acc[4]  += b2f_lo(v0.z); acc[5]  += b2f_hi(v0.z);
    acc[6]  += b2f_lo(v0.w); acc[7]  += b2f_hi(v0.w);
    acc[8]  += b2f_lo(v1.x); acc[9]  += b2f_hi(v1.x);
    acc[10] += b2f_lo(v1.y); acc[11] += b2f_hi(v1.y);
    acc[12] += b2f_lo(v1.z); acc[13] += b2f_hi(v1.z);
    acc[14] += b2f_lo(v1.w); acc[15] += b2f_hi(v1.w);
}

// ---------------- fp32 -> bf16 copy of x ----------------

__global__ void cvt_kernel(const float* __restrict__ in, u16* __restrict__ outb) {
    int i = blockIdx.x * 256 + threadIdx.x;
    if (i < NN * DD / 8) {
        float4 a = *(const float4*)&in[i * 8];
        float4 b = *(const float4*)&in[i * 8 + 4];
        uint4 o;
        o.x = pk(a.x, a.y); o.y = pk(a.z, a.w);
        o.z = pk(b.x, b.y); o.w = pk(b.z, b.w);
        *(uint4*)&outb[i * 8] = o;
    }
}

// ---------------- weight pre-transpose: Wt[d][k] bf16, all 36 matrices ----------------

__global__ void wt_kernel(const float* __restrict__ W1, const float* __restrict__ rW1,
                          const float* __restrict__ W2, const float* __restrict__ rW2,
                          u16* __restrict__ wt1g, u16* __restrict__ wt2g) {
    int m = blockIdx.x;                  // 0..35
    int i = m / 18, rest = m % 18;
    int set = rest / 9, r = rest % 9;
    const float* W = (set == 0)
        ? ((r < NR) ? (W1 + ((size_t)i * NR + r) * DD * DD) : (rW1 + (size_t)i * DD * DD))
        : ((r < NR) ? (W2 + ((size_t)i * NR + r) * DD * DD) : (rW2 + (size_t)i * DD * DD));
    u32* dst = (u32*)((set == 0 ? wt1g : wt2g) + ((size_t)i * 9 + r) * DD * DD);
    for (int j = threadIdx.x; j < DD * 32; j += 256) {
        int d = j >> 5, kp = j & 31;
        dst[j] = pk(W[(2 * kp) * DD + d], W[(2 * kp + 1) * DD + d]);
    }
}

// ---------------- dst-CSR build (once per call) ----------------

__global__ void count_kernel(const int* __restrict__ dst,
                             const int* __restrict__ et,
                             int* __restrict__ cnt) {
    int i = blockIdx.x * 256 + threadIdx.x;
    if (i < NE) atomicAdd(&cnt[et[i] * NTILES + (dst[i] >> 7)], 1);
}

__global__ void scan_kernel(const int* __restrict__ cnt, int* __restrict__ off, int n) {
    __shared__ int ts[1024];
    int t = threadIdx.x;
    int v[8];
    int s = 0;
#pragma unroll
    for (int j = 0; j < 8; j++) {
        int idx = t * 8 + j;
        int c = (idx < n) ? cnt[idx] : 0;
        v[j] = s;
        s += c;
    }
    ts[t] = s;
    __syncthreads();
    for (int d = 1; d < 1024; d <<= 1) {
        int add = (t >= d) ? ts[t - d] : 0;
        __syncthreads();
        ts[t] += add;
        __syncthreads();
    }
    int base = (t > 0) ? ts[t - 1] : 0;
#pragma unroll
    for (int j = 0; j < 8; j++) {
        int idx = t * 8 + j;
        if (idx < n) off[idx] = base + v[j];
    }
    if (t == 1023) off[n] = ts[1023];
}

__global__ void fill_kernel(const int* __restrict__ src, const int* __restrict__ dst,
                            const int* __restrict__ et, const int* __restrict__ off,
                            int* __restrict__ cursor, int* __restrict__ ep) {
    int i = blockIdx.x * 256 + threadIdx.x;
    if (i < NE) {
        int d = dst[i];
        int b = et[i] * NTILES + (d >> 7);
        int pos = off[b] + atomicAdd(&cursor[b], 1);
        ep[pos] = (src[i] << 8) | (d & 127);
    }
}

// ---------------- gemm1: 512-thread quarter-row gather -> bf16 LDS -> MFMA, BN stats ----------------

__launch_bounds__(512, 4)
__global__ void gemm1_kernel(const u16* __restrict__ xb,
                             const int* __restrict__ ep, const int* __restrict__ off,
                             const u16* __restrict__ wt1, const float* __restrict__ b1l,
                             const float* __restrict__ rb1l,
                             u16* __restrict__ zb, float* __restrict__ stats) {
    __shared__ u16 hsb[TILE * HROW];      // 18KB bf16 h-tile (then reused for z)
    __shared__ int seS[CAP], seD[CAP];
    __shared__ int shist[TILE], scur[TILE];
    __shared__ int soff[TILE + 1];
    __shared__ float red[2 * DD];
    int r = blockIdx.y;
    bool root = (r == NR);
    int n0 = blockIdx.x * TILE;
    int tid = threadIdx.x;

    int wv2 = tid >> 6;  // 0..7: MFMA wave -> rows wv2*16..+15
    int l  = tid & 63;
    int lr = l & 15;     // A row / B col / D col
    int lg = l >> 4;     // k-group / D row-group

    if (tid < 128) red[tid] = 0.f;

    if (!root) {
        int b = r * NTILES + blockIdx.x;
        int e0 = off[b], e1 = off[b + 1];
        int m = e1 - e0;
        int slot = tid >> 2, quarter = tid & 3;   // 4-lane group = one full 128B x-row
        int c0 = quarter * 16;
        float acc[16];
#pragma unroll
        for (int j = 0; j < 16; j++) acc[j] = 0.f;

        for (int base = 0; base < m; base += CAP) {
            int cnt = min(m - base, CAP);
            if (tid < TILE) shist[tid] = 0;
            __syncthreads();                       // (a) hist zeroed; prev gather done
            for (int i = tid; i < cnt; i += 512) {
                int p = ep[e0 + base + i];
                seS[i] = p;
                atomicAdd(&shist[p & 127], 1);
            }
            __syncthreads();                       // (b) hist complete
            if (tid < 64) {
                // single-wave scan of 128 counters: lane t owns entries t and t+64
                int c0s = shist[tid], c1s = shist[tid + 64];
                int s0 = c0s, s1 = c1s;
#pragma unroll
                for (int d = 1; d < 64; d <<= 1) {
                    int t0 = __shfl_up(s0, d);
                    int t1 = __shfl_up(s1, d);
                    if (tid >= d) { s0 += t0; s1 += t1; }
                }
                int tot0 = __shfl(s0, 63);
                soff[tid + 1]  = s0;
                soff[tid + 65] = tot0 + s1;
                if (tid == 0) soff[0] = 0;
                scur[tid]      = s0 - c0s;
                scur[tid + 64] = tot0 + s1 - c1s;
            }
            __syncthreads();                       // (c) soff/scur ready
            for (int i = tid; i < cnt; i += 512) {
                int p = seS[i];
                seD[atomicAdd(&scur[p & 127], 1)] = p;
            }
            __syncthreads();                       // (d) seD sorted
            int sb = soff[slot], se = soff[slot + 1];
            int e = sb;
            for (; e + 4 <= se; e += 4) {          // 4-edge unroll: 8 uint4 in flight
                const u16* x0p = &xb[(size_t)(seD[e]     >> 8) * DD + c0];
                const u16* x1p = &xb[(size_t)(seD[e + 1] >> 8) * DD + c0];
                const u16* x2p = &xb[(size_t)(seD[e + 2] >> 8) * DD + c0];
                const u16* x3p = &xb[(size_t)(seD[e + 3] >> 8) * DD + c0];
                uint4 a0 = *(const uint4*)(x0p), a1 = *(const uint4*)(x0p + 8);
                uint4 b0 = *(const uint4*)(x1p), b1 = *(const uint4*)(x1p + 8);
                uint4 cc0 = *(const uint4*)(x2p), cc1 = *(const uint4*)(x2p + 8);
                uint4 d0 = *(const uint4*)(x3p), d1 = *(const uint4*)(x3p + 8);
                acc4(acc, a0, a1);
                acc4(acc, b0, b1);
                acc4(acc, cc0, cc1);
                acc4(acc, d0, d1);
            }
            for (; e < se; e++) {
                const u16* xr = &xb[(size_t)(seD[e] >> 8) * DD + c0];
                acc4(acc, *(const uint4*)(xr), *(const uint4*)(xr + 8));
            }
        }
        // pack h to bf16 (16 floats -> 2 uint4)
        u32 pw[8];
#pragma unroll
        for (int j = 0; j < 8; j++) pw[j] = pk(acc[2 * j], acc[2 * j + 1]);
        u16* hrow = &hsb[slot * HROW + c0];
        *(uint4*)(hrow)     = make_uint4(pw[0], pw[1], pw[2], pw[3]);
        *(uint4*)(hrow + 8) = make_uint4(pw[4], pw[5], pw[6], pw[7]);
    } else {
        for (int idx = tid; idx < TILE * 8; idx += 512) {
            int row = idx >> 3, q = idx & 7;
            int n = n0 + row;
            uint4 v = make_uint4(0, 0, 0, 0);
            if (n < NN) v = *(const uint4*)&xb[(size_t)n * DD + q * 8];
            *(uint4*)&hsb[row * HROW + q * 8] = v;
        }
    }

    // B fragments from pre-transposed global Wt (L2-hot), short liveness: right before MFMA
    const u16* wtg = wt1 + (size_t)r * DD * DD;
    short8 bfrg[2][4];
#pragma unroll
    for (int ks = 0; ks < 2; ks++)
#pragma unroll
        for (int ct = 0; ct < 4; ct++)
            bfrg[ks][ct] = *(const short8*)&wtg[(ct * 16 + lr) * DD + ks * 32 + lg * 8];
    __syncthreads();

    // ---- MFMA: 8 waves, wave wv2 owns rows wv2*16..+15, all 64 cols ----
    f32x4 dacc[4];
#pragma unroll
    for (int ct = 0; ct < 4; ct++) dacc[ct] = (f32x4){0.f, 0.f, 0.f, 0.f};

#pragma unroll
    for (int ks = 0; ks < 2; ks++) {
        short8 afr = *(const short8*)&hsb[(wv2 * 16 + lr) * HROW + ks * 32 + lg * 8];
#pragma unroll
        for (int ct = 0; ct < 4; ct++)
            dacc[ct] = __builtin_amdgcn_mfma_f32_16x16x32_bf16(afr, bfrg[ks][ct], dacc[ct], 0, 0, 0);
    }

    // bias + BN stats (per-lane cols 16ct+lr, rows wv2*16+lg*4+i)
    const float* bvec = root ? rb1l : (b1l + r * DD);
    float bv4[4], s1v[4], s2v[4];
#pragma unroll
    for (int ct = 0; ct < 4; ct++) { bv4[ct] = bvec[16 * ct + lr]; s1v[ct] = 0.f; s2v[ct] = 0.f; }
#pragma unroll
    for (int ct = 0; ct < 4; ct++)
#pragma unroll
        for (int i = 0; i < 4; i++) {
            float v = dacc[ct][i] + bv4[ct];
            dacc[ct][i] = v;
            int n = n0 + wv2 * 16 + lg * 4 + i;
            if (n < NN) { s1v[ct] += v; s2v[ct] += v * v; }
        }
#pragma unroll
    for (int ct = 0; ct < 4; ct++) {
        float a = s1v[ct], bq = s2v[ct];
        a += __shfl_xor(a, 16); bq += __shfl_xor(bq, 16);
        a += __shfl_xor(a, 32); bq += __shfl_xor(bq, 32);
        if (lg == 0) {
            atomicAdd(&red[16 * ct + lr], a);
            atomicAdd(&red[64 + 16 * ct + lr], bq);
        }
    }
    __syncthreads();   // hsb reads done; red complete

    // scatter z (bf16) into hsb, then coalesced flush
#pragma unroll
    for (int ct = 0; ct < 4; ct++)
#pragma unroll
        for (int i = 0; i < 4; i++)
            hsb[(wv2 * 16 + lg * 4 + i) * HROW + 16 * ct + lr] = f2b(dacc[ct][i]);
    __syncthreads();

    u16* zout = zb + (size_t)r * NN * DD;
    for (int idx = tid; idx < TILE * 8; idx += 512) {
        int row = idx >> 3, q = idx & 7;
        int n = n0 + row;
        if (n < NN)
            *(uint4*)&zout[(size_t)n * DD + q * 8] = *(const uint4*)&hsb[row * HROW + q * 8];
    }
    if (tid < 64) {
        atomicAdd(&stats[r * DD + tid], red[tid]);
        atomicAdd(&stats[576 + r * DD + tid], red[64 + tid]);
    }
}

// ---------------- finalize: BN affine + fused const bias ----------------

__global__ void finalize_kernel(const float* __restrict__ stats,
                                const float* __restrict__ g1l, const float* __restrict__ be1l,
                                const float* __restrict__ rg1l, const float* __restrict__ rbe1l,
                                const float* __restrict__ b2l, const float* __restrict__ rb2l,
                                const float* __restrict__ biasl,
                                float* __restrict__ affine, float* __restrict__ constd) {
    int t = threadIdx.x;
    if (t < 576) {
        int r = t >> 6, d = t & 63;
        float mean = stats[t] * (1.f / NN);
        float var = fmaxf(stats[576 + t] * (1.f / NN) - mean * mean, 0.f);
        float g  = (r < NR) ? g1l[r * DD + d]  : rg1l[d];
        float be = (r < NR) ? be1l[r * DD + d] : rbe1l[d];
        float sc = g * rsqrtf(var + EPSB);
        affine[t] = sc;
        affine[576 + t] = be - mean * sc;
        if (r == 0) {
            float cd = rb2l[d] + biasl[d];
#pragma unroll
            for (int rr = 0; rr < NR; rr++) cd += b2l[rr * DD + d];
            constd[d] = cd;
        }
    }
}

// ---------------- pass2: MFMA out = sum_r relu(bn(z_r)) @ W2_r + const ----------------

__launch_bounds__(256, 4)
__global__ void pass2_kernel(const u16* __restrict__ zb, const u16* __restrict__ wt2,
                             const float* __restrict__ affine, const float* __restrict__ constd,
                             float* __restrict__ outf, u16* __restrict__ outb,
                             int emit_bf16_relu) {
    __shared__ u16 zsb[TILE * HROW];      // 18KB bf16 activated z-tile (reused for output)
    __shared__ u16 wtb[DD * HROW];        // 9KB Wt[d][k]
    int n0 = blockIdx.x * TILE;
    int tid = threadIdx.x;
    int srow = tid >> 3;          // staging row base (0..31), rows srow+32q
    int sc0 = (tid & 7) * 8;      // staging col base

    int wv = tid >> 6;
    int l  = tid & 63;
    int lr = l & 15;
    int lg = l >> 4;

    f32x4 dacc[2][4];
#pragma unroll
    for (int rt = 0; rt < 2; rt++)
#pragma unroll
        for (int ct = 0; ct < 4; ct++) dacc[rt][ct] = (f32x4){0.f, 0.f, 0.f, 0.f};

    uint4 preA[4], preB[4];
    u32 wreg[8];
#pragma unroll
    for (int q = 0; q < 4; q++) {
        int n = n0 + srow + 32 * q;
        preA[q] = (n < NN) ? *(const uint4*)&zb[(size_t)n * DD + sc0] : make_uint4(0, 0, 0, 0);
        preB[q] = (n < NN) ? *(const uint4*)&zb[(size_t)NN * DD + (size_t)n * DD + sc0]
                           : make_uint4(0, 0, 0, 0);
    }
    // prologue: W2t[0] into registers
    {
        const u32* wsrc = (const u32*)wt2;
#pragma unroll
        for (int j = 0; j < 8; j++) wreg[j] = wsrc[tid + 256 * j];
    }

#pragma unroll
    for (int r = 0; r < 9; r++) {
        uint4* cur = (r & 1) ? preB : preA;   // compile-time after unroll
        float4 aLo = *(const float4*)&affine[r * DD + sc0];
        float4 aHi = *(const float4*)&affine[r * DD + sc0 + 4];
        float4 cLo = *(const float4*)&affine[576 + r * DD + sc0];
        float4 cHi = *(const float4*)&affine[576 + r * DD + sc0 + 4];
        __syncthreads();   // previous iteration's MFMA frag-reads done
        // write activated tile (bf16) into zsb
#pragma unroll
        for (int q = 0; q < 4; q++) {
            uint4 vv = cur[q];
            float a0 = fmaxf(fmaf(b2f_lo(vv.x), aLo.x, cLo.x), 0.f);
            float a1 = fmaxf(fmaf(b2f_hi(vv.x), aLo.y, cLo.y), 0.f);
            float a2 = fmaxf(fmaf(b2f_lo(vv.y), aLo.z, cLo.z), 0.f);
            float a3 = fmaxf(fmaf(b2f_hi(vv.y), aLo.w, cLo.w), 0.f);
            float a4 = fmaxf(fmaf(b2f_lo(vv.z), aHi.x, cHi.x), 0.f);
            float a5 = fmaxf(fmaf(b2f_hi(vv.z), aHi.y, cHi.y), 0.f);
            float a6 = fmaxf(fmaf(b2f_lo(vv.w), aHi.z, cHi.z), 0.f);
            float a7 = fmaxf(fmaf(b2f_hi(vv.w), aHi.w, cHi.w), 0.f);
            uint4 o = make_uint4(pk(a0, a1), pk(a2, a3), pk(a4, a5), pk(a6, a7));
            *(uint4*)&zsb[(srow + 32 * q) * HROW + sc0] = o;
        }
        // write W2t from prefetched registers (loaded during previous MFMA)
        {
            int row = tid >> 5, q = tid & 31;     // tid -> (row, dword) ; 8 rows per burst
#pragma unroll
            for (int j = 0; j < 8; j++)
                ((u32*)&wtb[(row + 8 * j) * HROW])[q] = wreg[j];
        }
        __syncthreads();
        // issue W2t loads for r+1 and z loads for r+2 (fly during MFMA)
        if (r + 1 < 9) {
            const u32* wsrc = (const u32*)(wt2 + (size_t)(r + 1) * DD * DD);
#pragma unroll
            for (int j = 0; j < 8; j++) wreg[j] = wsrc[tid + 256 * j];
        }
        if (r + 2 < 9) {
            const u16* zp = zb + (size_t)(r + 2) * NN * DD;
#pragma unroll
            for (int q = 0; q < 4; q++) {
                int n = n0 + srow + 32 * q;
                cur[q] = (n < NN) ? *(const uint4*)&zp[(size_t)n * DD + sc0]
                                  : make_uint4(0, 0, 0, 0);
            }
        }
        // MFMA
#pragma unroll
        for (int ks = 0; ks < 2; ks++) {
            short8 afr[2];
#pragma unroll
            for (int rt = 0; rt < 2; rt++)
                afr[rt] = *(const short8*)&zsb[(wv * 32 + rt * 16 + lr) * HROW + ks * 32 + lg * 8];
#pragma unroll
            for (int ct = 0; ct < 4; ct++) {
                short8 bfr = *(const short8*)&wtb[(ct * 16 + lr) * HROW + ks * 32 + lg * 8];
                dacc[0][ct] = __builtin_amdgcn_mfma_f32_16x16x32_bf16(afr[0], bfr, dacc[0][ct], 0, 0, 0);
                dacc[1][ct] = __builtin_amdgcn_mfma_f32_16x16x32_bf16(afr[1], bfr, dacc[1][ct], 0, 0, 0);
            }
        }
    }

    float cd4[4];
#pragma unroll
    for (int ct = 0; ct < 4; ct++) cd4[ct] = constd[16 * ct + lr];

    if (emit_bf16_relu) {
        __syncthreads();
#pragma unroll
        for (int rt = 0; rt < 2; rt++)
#pragma unroll
            for (int ct = 0; ct < 4; ct++)
#pragma unroll
                for (int i = 0; i < 4; i++) {
                    float v = fmaxf(dacc[rt][ct][i] + cd4[ct], 0.f);
                    zsb[(wv * 32 + rt * 16 + lg * 4 + i) * HROW + 16 * ct + lr] = f2b(v);
                }
        __syncthreads();
        for (int idx = tid; idx < TILE * 8; idx += 256) {
            int row = idx >> 3, q = idx & 7;
            int n = n0 + row;
            if (n < NN)
                *(uint4*)&outb[(size_t)n * DD + q * 8] = *(const uint4*)&zsb[row * HROW + q * 8];
        }
    } else {
        float* zf = (float*)zsb;   // 128 x 34 f32 fits in 18KB
#pragma unroll
        for (int h = 0; h < 2; h++) {
            __syncthreads();
#pragma unroll
            for (int rt = 0; rt < 2; rt++)
#pragma unroll
                for (int cc = 0; cc < 2; cc++) {
                    int ct = 2 * h + cc;
#pragma unroll
                    for (int i = 0; i < 4; i++)
                        zf[(wv * 32 + rt * 16 + lg * 4 + i) * 34 + 16 * cc + lr] =
                            dacc[rt][ct][i] + cd4[ct];
                }
            __syncthreads();
            for (int idx = tid; idx < TILE * 8; idx += 256) {
                int row = idx >> 3, q = idx & 7;
                int n = n0 + row;
                if (n < NN)
                    *(float4*)&outf[(size_t)n * DD + 32 * h + q * 4] =
                        *(const float4*)&zf[row * 34 + q * 4];
            }
        }
    }
}

// ---------------- host ----------------

extern "C" void kernel_launch(void* const* d_in, const int* in_sizes, int n_in,
                              void* d_out, int out_size, void* d_ws, size_t ws_size,
                              hipStream_t stream) {
    (void)in_sizes; (void)n_in; (void)out_size;

    const float* x0   = (const float*)d_in[0];
    const int*   ei   = (const int*)d_in[1];
    const int*   et   = (const int*)d_in[2];
    const float* W1   = (const float*)d_in[3];
    const float* b1   = (const float*)d_in[4];
    const float* g1   = (const float*)d_in[5];
    const float* be1  = (const float*)d_in[6];
    const float* W2   = (const float*)d_in[7];
    const float* b2   = (const float*)d_in[8];
    const float* rW1  = (const float*)d_in[9];
    const float* rb1  = (const float*)d_in[10];
    const float* rg1  = (const float*)d_in[11];
    const float* rbe1 = (const float*)d_in[12];
    const float* rW2  = (const float*)d_in[13];
    const float* rb2  = (const float*)d_in[14];
    const float* bias = (const float*)d_in[15];
    float* out = (float*)d_out;

    char* ws = (char*)d_ws;
    size_t zelems = (size_t)9 * NN * DD;
    u16* zb   = (u16*)ws;                             // 9*NN*DD bf16
    u16* xb   = zb + zelems;                          // NN*DD bf16
    u16* wt1g = xb + (size_t)NN * DD;                 // 9*4096 bf16 x2 layers
    u16* wt2g = wt1g + 18 * DD * DD;
    float* stats  = (float*)(wt2g + 18 * DD * DD);    // 2*1152 (per-layer)
    float* affine = stats + 2304;                     // 1152
    float* constd = affine + 1152;                    // 64
    int* cnt    = (int*)(constd + 64);                // NBUCKETS
    int* cursor = cnt + NBUCKETS;                     // NBUCKETS
    int* off    = cursor + NBUCKETS;                  // NBUCKETS+1
    int* ep     = off + NBUCKETS + 1;                 // NE

    size_t need = (zelems + (size_t)NN * DD + 36 * DD * DD) * 2
                + (2304 + 1152 + 64) * 4
                + ((size_t)3 * NBUCKETS + 1 + NE) * 4;
    if (ws_size < need) return;

    cvt_kernel<<<(NN * DD / 8 + 255) / 256, 256, 0, stream>>>(x0, xb);
    wt_kernel<<<36, 256, 0, stream>>>(W1, rW1, W2, rW2, wt1g, wt2g);
    hipMemsetAsync(cnt, 0, sizeof(int) * 2 * NBUCKETS, stream);
    hipMemsetAsync(stats, 0, sizeof(float) * 2304, stream);
    count_kernel<<<(NE + 255) / 256, 256, 0, stream>>>(ei + NE, et, cnt);
    scan_kernel<<<1, 1024, 0, stream>>>(cnt, off, NBUCKETS);
    fill_kernel<<<(NE + 255) / 256, 256, 0, stream>>>(ei, ei + NE, et, off, cursor, ep);

    for (int i = 0; i < 2; i++) {
        gemm1_kernel<<<dim3(NTILES, 9), 512, 0, stream>>>(
            xb, ep, off,
            wt1g + (size_t)i * 9 * DD * DD,
            b1 + (size_t)i * NR * DD, rb1 + (size_t)i * DD,
            zb, stats + (size_t)i * 1152);
        finalize_kernel<<<1, 576, 0, stream>>>(
            stats + (size_t)i * 1152,
            g1 + (size_t)i * NR * DD, be1 + (size_t)i * NR * DD,
            rg1 + (size_t)i * DD, rbe1 + (size_t)i * DD,
            b2 + (size_t)i * NR * DD, rb2 + (size_t)i * DD, bias + (size_t)i * DD,
            affine, constd);
        pass2_kernel<<<NTILES, 256, 0, stream>>>(
            zb, wt2g + (size_t)i * 9 * DD * DD,
            affine, constd, out, xb, (i == 0) ? 1 : 0);
    }
}

// Round 19
// 450.187 us; speedup vs baseline: 1.2512x; 1.1584x over previous
//
#include <hip/hip_runtime.h>

#define NN 100000
#define NE 1250000
#define NR 8
#define DD 64
#define TILE 128
#define NTILES 782                 // ceil(100000/128)
#define NBUCKETS (NR * NTILES)     // 6256 dst-buckets (rel, dst-tile)
#define CAP 512                    // sort-chunk size (Poisson(200): 1 chunk typical)
#define HROW 72                    // bf16 LDS row stride (144B: conflict-free b128 frags)
#define EPSB 1e-5f

typedef unsigned short u16;
typedef unsigned int u32;
typedef __attribute__((ext_vector_type(8))) short short8;   // 8 bf16 = 4 VGPR (MFMA A/B frag)
typedef __attribute__((ext_vector_type(4))) float f32x4;    // MFMA C/D frag

static __device__ __forceinline__ float b2f_lo(u32 v) { return __uint_as_float(v << 16); }
static __device__ __forceinline__ float b2f_hi(u32 v) { return __uint_as_float(v & 0xffff0000u); }
static __device__ __forceinline__ u16 f2b(float f) {
    u32 u = __float_as_uint(f);
    u += 0x7fffu + ((u >> 16) & 1u);   // round-to-nearest-even
    return (u16)(u >> 16);
}
static __device__ __forceinline__ u32 pk(float a, float b) {
    return (u32)f2b(a) | ((u32)f2b(b) << 16);
}
// FINAL STATE (R16 config, measured 452-464us). Session-verified constraints:
// - 2-edge unroll (8 uint4 live) is the spill wall; deeper unrolls spill (R15/R17).
// - launch_bounds min-waves>4 caps VGPR at 40 -> always spills (R12/R17).
// - 512-thread quarter-row gather: clean but SLOWER (R18, 161 vs 128us).
// - LDS atomics were the original 4x bottleneck (R9); do not reintroduce.
static __device__ __forceinline__ void acc8(float* acc, uint4 v0, uint4 v1, uint4 v2, uint4 v3) {
#pragma unroll
    for (int q = 0; q < 4; q++) {
        uint4 v = (q == 0) ? v0 : (q == 1) ? v1 : (q == 2) ? v2 : v3;
        acc[q * 8 + 0] += b2f_lo(v.x);
        acc[q * 8 + 1] += b2f_hi(v.x);
        acc[q * 8 + 2] += b2f_lo(v.y);
        acc[q * 8 + 3] += b2f_hi(v.y);
        acc[q * 8 + 4] += b2f_lo(v.z);
        acc[q * 8 + 5] += b2f_hi(v.z);
        acc[q * 8 + 6] += b2f_lo(v.w);
        acc[q * 8 + 7] += b2f_hi(v.w);
    }
}

// ---------------- fp32 -> bf16 copy of x ----------------

__global__ void cvt_kernel(const float* __restrict__ in, u16* __restrict__ outb) {
    int i = blockIdx.x * 256 + threadIdx.x;
    if (i < NN * DD / 8) {
        float4 a = *(const float4*)&in[i * 8];
        float4 b = *(const float4*)&in[i * 8 + 4];
        uint4 o;
        o.x = pk(a.x, a.y); o.y = pk(a.z, a.w);
        o.z = pk(b.x, b.y); o.w = pk(b.z, b.w);
        *(uint4*)&outb[i * 8] = o;
    }
}

// ---------------- weight pre-transpose: Wt[d][k] bf16, all 36 matrices ----------------

__global__ void wt_kernel(const float* __restrict__ W1, const float* __restrict__ rW1,
                          const float* __restrict__ W2, const float* __restrict__ rW2,
                          u16* __restrict__ wt1g, u16* __restrict__ wt2g) {
    int m = blockIdx.x;                  // 0..35
    int i = m / 18, rest = m % 18;
    int set = rest / 9, r = rest % 9;
    const float* W = (set == 0)
        ? ((r < NR) ? (W1 + ((size_t)i * NR + r) * DD * DD) : (rW1 + (size_t)i * DD * DD))
        : ((r < NR) ? (W2 + ((size_t)i * NR + r) * DD * DD) : (rW2 + (size_t)i * DD * DD));
    u32* dst = (u32*)((set == 0 ? wt1g : wt2g) + ((size_t)i * 9 + r) * DD * DD);
    for (int j = threadIdx.x; j < DD * 32; j += 256) {
        int d = j >> 5, kp = j & 31;
        dst[j] = pk(W[(2 * kp) * DD + d], W[(2 * kp + 1) * DD + d]);
    }
}

// ---------------- dst-CSR build (once per call) ----------------

__global__ void count_kernel(const int* __restrict__ dst,
                             const int* __restrict__ et,
                             int* __restrict__ cnt) {
    int i = blockIdx.x * 256 + threadIdx.x;
    if (i < NE) atomicAdd(&cnt[et[i] * NTILES + (dst[i] >> 7)], 1);
}

__global__ void scan_kernel(const int* __restrict__ cnt, int* __restrict__ off, int n) {
    __shared__ int ts[1024];
    int t = threadIdx.x;
    int v[8];
    int s = 0;
#pragma unroll
    for (int j = 0; j < 8; j++) {
        int idx = t * 8 + j;
        int c = (idx < n) ? cnt[idx] : 0;
        v[j] = s;
        s += c;
    }
    ts[t] = s;
    __syncthreads();
    for (int d = 1; d < 1024; d <<= 1) {
        int add = (t >= d) ? ts[t - d] : 0;
        __syncthreads();
        ts[t] += add;
        __syncthreads();
    }
    int base = (t > 0) ? ts[t - 1] : 0;
#pragma unroll
    for (int j = 0; j < 8; j++) {
        int idx = t * 8 + j;
        if (idx < n) off[idx] = base + v[j];
    }
    if (t == 1023) off[n] = ts[1023];
}

__global__ void fill_kernel(const int* __restrict__ src, const int* __restrict__ dst,
                            const int* __restrict__ et, const int* __restrict__ off,
                            int* __restrict__ cursor, int* __restrict__ ep) {
    int i = blockIdx.x * 256 + threadIdx.x;
    if (i < NE) {
        int d = dst[i];
        int b = et[i] * NTILES + (d >> 7);
        int pos = off[b] + atomicAdd(&cursor[b], 1);
        ep[pos] = (src[i] << 8) | (d & 127);
    }
}

// ---------------- gemm1: sort+register gather -> bf16 LDS -> MFMA z=h@W1+b1, BN stats ----------------

__launch_bounds__(256, 4)
__global__ void gemm1_kernel(const u16* __restrict__ xb,
                             const int* __restrict__ ep, const int* __restrict__ off,
                             const u16* __restrict__ wt1, const float* __restrict__ b1l,
                             const float* __restrict__ rb1l,
                             u16* __restrict__ zb, float* __restrict__ stats) {
    __shared__ u16 hsb[TILE * HROW];      // 18KB bf16 h-tile (then reused for z)
    __shared__ int seS[CAP], seD[CAP];
    __shared__ int shist[TILE], scur[TILE];
    __shared__ int soff[TILE + 1];
    __shared__ float red[2 * DD];
    int r = blockIdx.y;
    bool root = (r == NR);
    int n0 = blockIdx.x * TILE;
    int tid = threadIdx.x;

    int wv = tid >> 6;
    int l  = tid & 63;
    int lr = l & 15;    // A row / B col / D col
    int lg = l >> 4;    // k-group / D row-group

    if (tid < 128) red[tid] = 0.f;

    if (!root) {
        int b = r * NTILES + blockIdx.x;
        int e0 = off[b], e1 = off[b + 1];
        int m = e1 - e0;
        int slot = tid & 127, half = tid >> 7;
        float acc[32];
#pragma unroll
        for (int j = 0; j < 32; j++) acc[j] = 0.f;

        for (int base = 0; base < m; base += CAP) {
            int cnt = min(m - base, CAP);
            if (tid < TILE) shist[tid] = 0;
            __syncthreads();                       // (a) hist zeroed; prev gather done
            for (int i = tid; i < cnt; i += 256) {
                int p = ep[e0 + base + i];
                seS[i] = p;
                atomicAdd(&shist[p & 127], 1);
            }
            __syncthreads();                       // (b) hist complete
            if (tid < 64) {
                // single-wave scan of 128 counters: lane t owns entries t and t+64
                int c0 = shist[tid], c1 = shist[tid + 64];
                int s0 = c0, s1 = c1;
#pragma unroll
                for (int d = 1; d < 64; d <<= 1) {
                    int t0 = __shfl_up(s0, d);
                    int t1 = __shfl_up(s1, d);
                    if (tid >= d) { s0 += t0; s1 += t1; }
                }
                int tot0 = __shfl(s0, 63);
                soff[tid + 1]  = s0;
                soff[tid + 65] = tot0 + s1;
                if (tid == 0) soff[0] = 0;
                scur[tid]      = s0 - c0;
                scur[tid + 64] = tot0 + s1 - c1;
            }
            __syncthreads();                       // (c) soff/scur ready
            for (int i = tid; i < cnt; i += 256) {
                int p = seS[i];
                seD[atomicAdd(&scur[p & 127], 1)] = p;
            }
            __syncthreads();                       // (d) seD sorted
            int sb = soff[slot], se = soff[slot + 1];
            int e = sb;
            for (; e + 2 <= se; e += 2) {          // 2-edge unroll: 8 loads in flight
                const u16* xr0 = &xb[(size_t)(seD[e] >> 8) * DD + half * 32];
                const u16* xr1 = &xb[(size_t)(seD[e + 1] >> 8) * DD + half * 32];
                uint4 a0 = *(const uint4*)(xr0);      uint4 c0 = *(const uint4*)(xr1);
                uint4 a1 = *(const uint4*)(xr0 + 8);  uint4 c1 = *(const uint4*)(xr1 + 8);
                uint4 a2 = *(const uint4*)(xr0 + 16); uint4 c2 = *(const uint4*)(xr1 + 16);
                uint4 a3 = *(const uint4*)(xr0 + 24); uint4 c3 = *(const uint4*)(xr1 + 24);
                acc8(acc, a0, a1, a2, a3);
                acc8(acc, c0, c1, c2, c3);
            }
            if (e < se) {
                const u16* xr = &xb[(size_t)(seD[e] >> 8) * DD + half * 32];
                acc8(acc, *(const uint4*)(xr), *(const uint4*)(xr + 8),
                     *(const uint4*)(xr + 16), *(const uint4*)(xr + 24));
            }
        }
        // pack h to bf16, one conflict-free write burst per thread
        u32 pw[16];
#pragma unroll
        for (int j = 0; j < 16; j++) pw[j] = pk(acc[2 * j], acc[2 * j + 1]);
        u16* hrow = &hsb[slot * HROW + half * 32];
        *(uint4*)(hrow)      = make_uint4(pw[0], pw[1], pw[2], pw[3]);
        *(uint4*)(hrow + 8)  = make_uint4(pw[4], pw[5], pw[6], pw[7]);
        *(uint4*)(hrow + 16) = make_uint4(pw[8], pw[9], pw[10], pw[11]);
        *(uint4*)(hrow + 24) = make_uint4(pw[12], pw[13], pw[14], pw[15]);
    } else {
        for (int idx = tid; idx < TILE * 8; idx += 256) {
            int row = idx >> 3, q = idx & 7;
            int n = n0 + row;
            uint4 v = make_uint4(0, 0, 0, 0);
            if (n < NN) v = *(const uint4*)&xb[(size_t)n * DD + q * 8];
            *(uint4*)&hsb[row * HROW + q * 8] = v;
        }
    }

    // B fragments from pre-transposed global Wt (L2-hot), short liveness: right before MFMA
    const u16* wtg = wt1 + (size_t)r * DD * DD;
    short8 bfrg[2][4];
#pragma unroll
    for (int ks = 0; ks < 2; ks++)
#pragma unroll
        for (int ct = 0; ct < 4; ct++)
            bfrg[ks][ct] = *(const short8*)&wtg[(ct * 16 + lr) * DD + ks * 32 + lg * 8];
    __syncthreads();

    // ---- MFMA: wave w owns rows 32w..32w+31, all 64 cols ----
    f32x4 dacc[2][4];
#pragma unroll
    for (int rt = 0; rt < 2; rt++)
#pragma unroll
        for (int ct = 0; ct < 4; ct++) dacc[rt][ct] = (f32x4){0.f, 0.f, 0.f, 0.f};

#pragma unroll
    for (int ks = 0; ks < 2; ks++) {
        short8 afr[2];
#pragma unroll
        for (int rt = 0; rt < 2; rt++)
            afr[rt] = *(const short8*)&hsb[(wv * 32 + rt * 16 + lr) * HROW + ks * 32 + lg * 8];
#pragma unroll
        for (int ct = 0; ct < 4; ct++) {
            dacc[0][ct] = __builtin_amdgcn_mfma_f32_16x16x32_bf16(afr[0], bfrg[ks][ct], dacc[0][ct], 0, 0, 0);
            dacc[1][ct] = __builtin_amdgcn_mfma_f32_16x16x32_bf16(afr[1], bfrg[ks][ct], dacc[1][ct], 0, 0, 0);
        }
    }

    // bias + BN stats (per-lane cols 16ct+lr, rows wv*32+rt*16+lg*4+i)
    const float* bvec = root ? rb1l : (b1l + r * DD);
    float bv4[4], s1v[4], s2v[4];
#pragma unroll
    for (int ct = 0; ct < 4; ct++) { bv4[ct] = bvec[16 * ct + lr]; s1v[ct] = 0.f; s2v[ct] = 0.f; }
#pragma unroll
    for (int rt = 0; rt < 2; rt++)
#pragma unroll
        for (int ct = 0; ct < 4; ct++)
#pragma unroll
            for (int i = 0; i < 4; i++) {
                float v = dacc[rt][ct][i] + bv4[ct];
                dacc[rt][ct][i] = v;
                int n = n0 + wv * 32 + rt * 16 + lg * 4 + i;
                if (n < NN) { s1v[ct] += v; s2v[ct] += v * v; }
            }
#pragma unroll
    for (int ct = 0; ct < 4; ct++) {
        float a = s1v[ct], bq = s2v[ct];
        a += __shfl_xor(a, 16); bq += __shfl_xor(bq, 16);
        a += __shfl_xor(a, 32); bq += __shfl_xor(bq, 32);
        if (lg == 0) {
            atomicAdd(&red[16 * ct + lr], a);
            atomicAdd(&red[64 + 16 * ct + lr], bq);
        }
    }
    __syncthreads();   // hsb reads done; red complete

    // scatter z (bf16) into hsb, then coalesced flush
#pragma unroll
    for (int rt = 0; rt < 2; rt++)
#pragma unroll
        for (int ct = 0; ct < 4; ct++)
#pragma unroll
            for (int i = 0; i < 4; i++)
                hsb[(wv * 32 + rt * 16 + lg * 4 + i) * HROW + 16 * ct + lr] = f2b(dacc[rt][ct][i]);
    __syncthreads();

    u16* zout = zb + (size_t)r * NN * DD;
    for (int idx = tid; idx < TILE * 8; idx += 256) {
        int row = idx >> 3, q = idx & 7;
        int n = n0 + row;
        if (n < NN)
            *(uint4*)&zout[(size_t)n * DD + q * 8] = *(const uint4*)&hsb[row * HROW + q * 8];
    }
    if (tid < 64) {
        atomicAdd(&stats[r * DD + tid], red[tid]);
        atomicAdd(&stats[576 + r * DD + tid], red[64 + tid]);
    }
}

// ---------------- finalize: BN affine + fused const bias ----------------

__global__ void finalize_kernel(const float* __restrict__ stats,
                                const float* __restrict__ g1l, const float* __restrict__ be1l,
                                const float* __restrict__ rg1l, const float* __restrict__ rbe1l,
                                const float* __restrict__ b2l, const float* __restrict__ rb2l,
                                const float* __restrict__ biasl,
                                float* __restrict__ affine, float* __restrict__ constd) {
    int t = threadIdx.x;
    if (t < 576) {
        int r = t >> 6, d = t & 63;
        float mean = stats[t] * (1.f / NN);
        float var = fmaxf(stats[576 + t] * (1.f / NN) - mean * mean, 0.f);
        float g  = (r < NR) ? g1l[r * DD + d]  : rg1l[d];
        float be = (r < NR) ? be1l[r * DD + d] : rbe1l[d];
        float sc = g * rsqrtf(var + EPSB);
        affine[t] = sc;
        affine[576 + t] = be - mean * sc;
        if (r == 0) {
            float cd = rb2l[d] + biasl[d];
#pragma unroll
            for (int rr = 0; rr < NR; rr++) cd += b2l[rr * DD + d];
            constd[d] = cd;
        }
    }
}

// ---------------- pass2: MFMA out = sum_r relu(bn(z_r)) @ W2_r + const ----------------

__launch_bounds__(256, 4)
__global__ void pass2_kernel(const u16* __restrict__ zb, const u16* __restrict__ wt2,
                             const float* __restrict__ affine, const float* __restrict__ constd,
                             float* __restrict__ outf, u16* __restrict__ outb,
                             int emit_bf16_relu) {
    __shared__ u16 zsb[TILE * HROW];      // 18KB bf16 activated z-tile (reused for output)
    __shared__ u16 wtb[DD * HROW];        // 9KB Wt[d][k]
    int n0 = blockIdx.x * TILE;
    int tid = threadIdx.x;
    int srow = tid >> 3;          // staging row base (0..31), rows srow+32q
    int sc0 = (tid & 7) * 8;      // staging col base

    int wv = tid >> 6;
    int l  = tid & 63;
    int lr = l & 15;
    int lg = l >> 4;

    f32x4 dacc[2][4];
#pragma unroll
    for (int rt = 0; rt < 2; rt++)
#pragma unroll
        for (int ct = 0; ct < 4; ct++) dacc[rt][ct] = (f32x4){0.f, 0.f, 0.f, 0.f};

    uint4 preA[4], preB[4];
    u32 wreg[8];
#pragma unroll
    for (int q = 0; q < 4; q++) {
        int n = n0 + srow + 32 * q;
        preA[q] = (n < NN) ? *(const uint4*)&zb[(size_t)n * DD + sc0] : make_uint4(0, 0, 0, 0);
        preB[q] = (n < NN) ? *(const uint4*)&zb[(size_t)NN * DD + (size_t)n * DD + sc0]
                           : make_uint4(0, 0, 0, 0);
    }
    // prologue: W2t[0] into registers
    {
        const u32* wsrc = (const u32*)wt2;
#pragma unroll
        for (int j = 0; j < 8; j++) wreg[j] = wsrc[tid + 256 * j];
    }

#pragma unroll
    for (int r = 0; r < 9; r++) {
        uint4* cur = (r & 1) ? preB : preA;   // compile-time after unroll
        float4 aLo = *(const float4*)&affine[r * DD + sc0];
        float4 aHi = *(const float4*)&affine[r * DD + sc0 + 4];
        float4 cLo = *(const float4*)&affine[576 + r * DD + sc0];
        float4 cHi = *(const float4*)&affine[576 + r * DD + sc0 + 4];
        __syncthreads();   // previous iteration's MFMA frag-reads done
        // write activated tile (bf16) into zsb
#pragma unroll
        for (int q = 0; q < 4; q++) {
            uint4 vv = cur[q];
            float a0 = fmaxf(fmaf(b2f_lo(vv.x), aLo.x, cLo.x), 0.f);
            float a1 = fmaxf(fmaf(b2f_hi(vv.x), aLo.y, cLo.y), 0.f);
            float a2 = fmaxf(fmaf(b2f_lo(vv.y), aLo.z, cLo.z), 0.f);
            float a3 = fmaxf(fmaf(b2f_hi(vv.y), aLo.w, cLo.w), 0.f);
            float a4 = fmaxf(fmaf(b2f_lo(vv.z), aHi.x, cHi.x), 0.f);
            float a5 = fmaxf(fmaf(b2f_hi(vv.z), aHi.y, cHi.y), 0.f);
            float a6 = fmaxf(fmaf(b2f_lo(vv.w), aHi.z, cHi.z), 0.f);
            float a7 = fmaxf(fmaf(b2f_hi(vv.w), aHi.w, cHi.w), 0.f);
            uint4 o = make_uint4(pk(a0, a1), pk(a2, a3), pk(a4, a5), pk(a6, a7));
            *(uint4*)&zsb[(srow + 32 * q) * HROW + sc0] = o;
        }
        // write W2t from prefetched registers (loaded during previous MFMA)
        {
            int row = tid >> 5, q = tid & 31;     // tid -> (row, dword) ; 8 rows per burst
#pragma unroll
            for (int j = 0; j < 8; j++)
                ((u32*)&wtb[(row + 8 * j) * HROW])[q] = wreg[j];
        }
        __syncthreads();
        // issue W2t loads for r+1 and z loads for r+2 (fly during MFMA)
        if (r + 1 < 9) {
            const u32* wsrc = (const u32*)(wt2 + (size_t)(r + 1) * DD * DD);
#pragma unroll
            for (int j = 0; j < 8; j++) wreg[j] = wsrc[tid + 256 * j];
        }
        if (r + 2 < 9) {
            const u16* zp = zb + (size_t)(r + 2) * NN * DD;
#pragma unroll
            for (int q = 0; q < 4; q++) {
                int n = n0 + srow + 32 * q;
                cur[q] = (n < NN) ? *(const uint4*)&zp[(size_t)n * DD + sc0]
                                  : make_uint4(0, 0, 0, 0);
            }
        }
        // MFMA
#pragma unroll
        for (int ks = 0; ks < 2; ks++) {
            short8 afr[2];
#pragma unroll
            for (int rt = 0; rt < 2; rt++)
                afr[rt] = *(const short8*)&zsb[(wv * 32 + rt * 16 + lr) * HROW + ks * 32 + lg * 8];
#pragma unroll
            for (int ct = 0; ct < 4; ct++) {
                short8 bfr = *(const short8*)&wtb[(ct * 16 + lr) * HROW + ks * 32 + lg * 8];
                dacc[0][ct] = __builtin_amdgcn_mfma_f32_16x16x32_bf16(afr[0], bfr, dacc[0][ct], 0, 0, 0);
                dacc[1][ct] = __builtin_amdgcn_mfma_f32_16x16x32_bf16(afr[1], bfr, dacc[1][ct], 0, 0, 0);
            }
        }
    }

    float cd4[4];
#pragma unroll
    for (int ct = 0; ct < 4; ct++) cd4[ct] = constd[16 * ct + lr];

    if (emit_bf16_relu) {
        __syncthreads();
#pragma unroll
        for (int rt = 0; rt < 2; rt++)
#pragma unroll
            for (int ct = 0; ct < 4; ct++)
#pragma unroll
                for (int i = 0; i < 4; i++) {
                    float v = fmaxf(dacc[rt][ct][i] + cd4[ct], 0.f);
                    zsb[(wv * 32 + rt * 16 + lg * 4 + i) * HROW + 16 * ct + lr] = f2b(v);
                }
        __syncthreads();
        for (int idx = tid; idx < TILE * 8; idx += 256) {
            int row = idx >> 3, q = idx & 7;
            int n = n0 + row;
            if (n < NN)
                *(uint4*)&outb[(size_t)n * DD + q * 8] = *(const uint4*)&zsb[row * HROW + q * 8];
        }
    } else {
        float* zf = (float*)zsb;   // 128 x 34 f32 fits in 18KB
#pragma unroll
        for (int h = 0; h < 2; h++) {
            __syncthreads();
#pragma unroll
            for (int rt = 0; rt < 2; rt++)
#pragma unroll
                for (int cc = 0; cc < 2; cc++) {
                    int ct = 2 * h + cc;
#pragma unroll
                    for (int i = 0; i < 4; i++)
                        zf[(wv * 32 + rt * 16 + lg * 4 + i) * 34 + 16 * cc + lr] =
                            dacc[rt][ct][i] + cd4[ct];
                }
            __syncthreads();
            for (int idx = tid; idx < TILE * 8; idx += 256) {
                int row = idx >> 3, q = idx & 7;
                int n = n0 + row;
                if (n < NN)
                    *(float4*)&outf[(size_t)n * DD + 32 * h + q * 4] =
                        *(const float4*)&zf[row * 34 + q * 4];
            }
        }
    }
}

// ---------------- host ----------------

extern "C" void kernel_launch(void* const* d_in, const int* in_sizes, int n_in,
                              void* d_out, int out_size, void* d_ws, size_t ws_size,
                              hipStream_t stream) {
    (void)in_sizes; (void)n_in; (void)out_size;

    const float* x0   = (const float*)d_in[0];
    const int*   ei   = (const int*)d_in[1];
    const int*   et   = (const int*)d_in[2];
    const float* W1   = (const float*)d_in[3];
    const float* b1   = (const float*)d_in[4];
    const float* g1   = (const float*)d_in[5];
    const float* be1  = (const float*)d_in[6];
    const float* W2   = (const float*)d_in[7];
    const float* b2   = (const float*)d_in[8];
    const float* rW1  = (const float*)d_in[9];
    const float* rb1  = (const float*)d_in[10];
    const float* rg1  = (const float*)d_in[11];
    const float* rbe1 = (const float*)d_in[12];
    const float* rW2  = (const float*)d_in[13];
    const float* rb2  = (const float*)d_in[14];
    const float* bias = (const float*)d_in[15];
    float* out = (float*)d_out;

    char* ws = (char*)d_ws;
    size_t zelems = (size_t)9 * NN * DD;
    u16* zb   = (u16*)ws;                             // 9*NN*DD bf16
    u16* xb   = zb + zelems;                          // NN*DD bf16
    u16* wt1g = xb + (size_t)NN * DD;                 // 9*4096 bf16 x2 layers
    u16* wt2g = wt1g + 18 * DD * DD;
    float* stats  = (float*)(wt2g + 18 * DD * DD);    // 2*1152 (per-layer)
    float* affine = stats + 2304;                     // 1152
    float* constd = affine + 1152;                    // 64
    int* cnt    = (int*)(constd + 64);                // NBUCKETS
    int* cursor = cnt + NBUCKETS;                     // NBUCKETS
    int* off    = cursor + NBUCKETS;                  // NBUCKETS+1
    int* ep     = off + NBUCKETS + 1;                 // NE

    size_t need = (zelems + (size_t)NN * DD + 36 * DD * DD) * 2
                + (2304 + 1152 + 64) * 4
                + ((size_t)3 * NBUCKETS + 1 + NE) * 4;
    if (ws_size < need) return;

    cvt_kernel<<<(NN * DD / 8 + 255) / 256, 256, 0, stream>>>(x0, xb);
    wt_kernel<<<36, 256, 0, stream>>>(W1, rW1, W2, rW2, wt1g, wt2g);
    hipMemsetAsync(cnt, 0, sizeof(int) * 2 * NBUCKETS, stream);
    hipMemsetAsync(stats, 0, sizeof(float) * 2304, stream);
    count_kernel<<<(NE + 255) / 256, 256, 0, stream>>>(ei + NE, et, cnt);
    scan_kernel<<<1, 1024, 0, stream>>>(cnt, off, NBUCKETS);
    fill_kernel<<<(NE + 255) / 256, 256, 0, stream>>>(ei, ei + NE, et, off, cursor, ep);

    for (int i = 0; i < 2; i++) {
        gemm1_kernel<<<dim3(NTILES, 9), 256, 0, stream>>>(
            xb, ep, off,
            wt1g + (size_t)i * 9 * DD * DD,
            b1 + (size_t)i * NR * DD, rb1 + (size_t)i * DD,
            zb, stats + (size_t)i * 1152);
        finalize_kernel<<<1, 576, 0, stream>>>(
            stats + (size_t)i * 1152,
            g1 + (size_t)i * NR * DD, be1 + (size_t)i * NR * DD,
            rg1 + (size_t)i * DD, rbe1 + (size_t)i * DD,
            b2 + (size_t)i * NR * DD, rb2 + (size_t)i * DD, bias + (size_t)i * DD,
            affine, constd);
        pass2_kernel<<<NTILES, 256, 0, stream>>>(
            zb, wt2g + (size_t)i * 9 * DD * DD,
            affine, constd, out, xb, (i == 0) ? 1 : 0);
    }
}